// Round 19
// baseline (920.931 us; speedup 1.0000x reference)
//
#include <hip/hip_runtime.h>

#define N_NODES 20000
#define N_EDGES 320000
#define EPB 48
#define NB2 6667              // ceil(N_EDGES/EPB)
#define ROWCAP 96

typedef __attribute__((ext_vector_type(4))) float f32x4;
typedef __attribute__((ext_vector_type(8))) short s16x8;

#define EXP2(x) exp2f(x)

// hardware RNE f32->bf16 (v_cvt_pk_bf16_f32): pair and scalar forms
__device__ __forceinline__ unsigned int pk2(float a, float b){
  unsigned int r;
  asm("v_cvt_pk_bf16_f32 %0, %1, %2" : "=v"(r) : "v"(a), "v"(b));
  return r;
}
__device__ __forceinline__ unsigned short f2b(float f){
  unsigned int r;
  asm("v_cvt_pk_bf16_f32 %0, %1, %1" : "=v"(r) : "v"(f));
  return (unsigned short)r;
}
__device__ __forceinline__ float b2f(unsigned short h){
  union { unsigned int u; float f; } v; v.u = ((unsigned int)h)<<16; return v.f;
}
__device__ __forceinline__ float sigm(float x){ return 1.0f/(1.0f+__expf(-x)); }
__device__ __forceinline__ float tanhfast(float x){ return 1.0f - 2.0f/(1.0f+__expf(2.0f*x)); }

// ---------------- fused: weight prep (0..831) + dual histogram (832..2081) + x->bf16 (2082..4581)
// WaB pre-scaled by log2(e) so k_attn uses exp2.
__global__ void k_init(const float* We, const float* Whu, const float* Whw,
                       const float* Wa, const float* Wi, const float* Wh,
                       unsigned short* WcatB, unsigned short* WaB,
                       unsigned short* WiB, unsigned short* WhB,
                       const int* ei, int* cnt, int* cnt2,
                       const float* x, unsigned short* xb){
  int b = blockIdx.x;
  if (b < 832){
    int i = b*256 + threadIdx.x;
    if (i < 49152){
      int d = i/384, k = i - d*384;
      float v = (k<128) ? We[d*128+k] : (k<256 ? Whu[d*128+k-128] : Whw[d*128+k-256]);
      WcatB[i] = f2b(v);
    } else if (i < 49152+65536){
      int j = i-49152; WaB[j] = f2b(Wa[j] * 1.4426950408889634f);
    } else if (i < 49152+65536+49152){
      int j = i-114688; WiB[j] = f2b(Wi[j]);
    } else if (i < 212992){
      int j = i-163840; WhB[j] = f2b(Wh[j]);
    }
  } else if (b < 2082){
    int e = (b-832)*256 + threadIdx.x;
    atomicAdd(&cnt[ei[e]], 1);
    atomicAdd(&cnt2[ei[N_EDGES + e]], 1);
  } else {
    int i = (b-2082)*256 + threadIdx.x;   // i in [0, 640000): one float4 each
    float4 v = *(const float4*)(x + (size_t)i*4);
    *(unsigned int*)(xb + (size_t)i*4)     = pk2(v.x, v.y);
    *(unsigned int*)(xb + (size_t)i*4 + 2) = pk2(v.z, v.w);
  }
}

// ---------------- scan: shfl-based
__global__ void k_scan(const int* cntA, const int* cntB, int* offA, int* offB,
                       int* curA, int* curB){
  const int* cnt = blockIdx.x ? cntB : cntA;
  int* off    = blockIdx.x ? offB : offA;
  int* cursor = blockIdx.x ? curB : curA;
  __shared__ int wsum[16];
  __shared__ int sbase;
  const int tid = threadIdx.x;
  const int wv = tid>>6, ln = tid&63;
  if (tid==0) sbase = 0;
  __syncthreads();
  for (int ch=0; ch<20; ++ch){
    int idx = ch*1024 + tid;
    int v = (idx < N_NODES) ? cnt[idx] : 0;
    int ps = v;
    #pragma unroll
    for (int s=1; s<64; s<<=1){
      int t = __shfl_up(ps, s, 64);
      if (ln >= s) ps += t;
    }
    if (ln==63) wsum[wv] = ps;
    __syncthreads();
    if (tid < 16){
      int wps = wsum[tid];
      #pragma unroll
      for (int s=1; s<16; s<<=1){
        int t = __shfl_up(wps, s, 64);
        if (tid >= s) wps += t;
      }
      wsum[tid] = wps;
    }
    __syncthreads();
    int base = sbase + (wv ? wsum[wv-1] : 0);
    int o = base + ps - v;
    if (idx < N_NODES){ off[idx] = o; cursor[idx] = o; }
    int total = wsum[15];
    __syncthreads();
    if (tid==0) sbase += total;
    __syncthreads();
  }
  if (tid==0) off[N_NODES] = sbase;
}

// ---------------- fused: blockmap (blocks 0..26) + dual scatter (27..1276)
__global__ void k_mid(const int* off, int* nfA, const int* ei,
                      int* cursor, int* cursor2, int* sorted, int* sortedT){
  int b = blockIdx.x;
  if (b < 27){
    int i = b*256 + threadIdx.x;
    if (i > NB2) return;
    int target = i*EPB;
    int lo = 0, hi = N_NODES;
    while (lo < hi){
      int mid = (lo + hi) >> 1;
      if (off[mid] < target) lo = mid + 1; else hi = mid;
    }
    nfA[i] = lo;
  } else {
    int e = (b-27)*256 + threadIdx.x;
    int s = ei[e];
    int t = ei[N_EDGES + e];
    int slot = atomicAdd(&cursor[s], 1);
    sorted[slot] = e;
    int slot2 = atomicAdd(&cursor2[t], 1);
    sortedT[slot2] = e;
  }
}

// ---------------- K1 (r13 form + xb gathers): messages = leaky(cat(ea,x[s],x[t]) @ Wcat^T)
__global__ __launch_bounds__(256,3) void k_messages(const float* ea, const int* ei,
                                                    const unsigned short* xb,
                                                    const unsigned short* WcatB,
                                                    float* msg_out){
  const int tid = threadIdx.x;
  const int e0 = blockIdx.x*64;
  __shared__ unsigned short A[64][392];
  const int w = tid>>6, l = tid&63, lr = l&15, lg = l>>4;
  s16x8 bfr[2][12];
  #pragma unroll
  for (int nt2=0; nt2<2; ++nt2){
    int colr = w*32 + nt2*16 + lr;
    #pragma unroll
    for (int ks=0; ks<12; ++ks)
      bfr[nt2][ks] = *(const s16x8*)(WcatB + colr*384 + ks*32 + lg*8);
  }
  {
    int i = tid>>2, q = tid&3;
    int e = e0 + i;
    int s = ei[e]; int t = ei[N_EDGES + e];
    const float* pe = ea + (size_t)e*128 + q*32;
    const unsigned short* ps = xb + (size_t)s*128 + q*32;
    const unsigned short* pt = xb + (size_t)t*128 + q*32;
    #pragma unroll
    for (int j=0;j<32;j+=8){
      float4 v0 = *(const float4*)(pe+j), v1 = *(const float4*)(pe+j+4);
      *(uint4*)&A[i][q*32+j] = (uint4){pk2(v0.x,v0.y),pk2(v0.z,v0.w),pk2(v1.x,v1.y),pk2(v1.z,v1.w)};
      *(uint4*)&A[i][128+q*32+j] = *(const uint4*)(ps+j);
      *(uint4*)&A[i][256+q*32+j] = *(const uint4*)(pt+j);
    }
  }
  __syncthreads();
  f32x4 acc[4][2];
  #pragma unroll
  for (int rt=0;rt<4;++rt)
    #pragma unroll
    for (int n2=0;n2<2;++n2) acc[rt][n2] = (f32x4){0.f,0.f,0.f,0.f};
  for (int ks=0; ks<12; ++ks){
    #pragma unroll
    for (int rt=0;rt<4;++rt){
      s16x8 af = *(const s16x8*)&A[rt*16 + lr][ks*32 + lg*8];
      acc[rt][0] = __builtin_amdgcn_mfma_f32_16x16x32_bf16(af, bfr[0][ks], acc[rt][0], 0,0,0);
      acc[rt][1] = __builtin_amdgcn_mfma_f32_16x16x32_bf16(af, bfr[1][ks], acc[rt][1], 0,0,0);
    }
  }
  #pragma unroll
  for (int rt=0;rt<4;++rt){
    #pragma unroll
    for (int n2=0;n2<2;++n2){
      int col = w*32 + n2*16 + lr;
      #pragma unroll
      for (int j=0;j<4;++j){
        int row = e0 + rt*16 + lg*4 + j;
        float v = acc[rt][n2][j];
        v = (v>0.f) ? v : 0.01f*v;
        msg_out[(size_t)row*128 + col] = v;
      }
    }
  }
}

// ---------------- K2: r16 form + h-pair-fused segment reduce (shared masks/control)
__global__ __launch_bounds__(256,5) void k_attn(const float* msg, unsigned short* phi,
                                                const unsigned short* WaB,
                                                const int* off, const int* sorted, const int* nfA){
  __shared__ unsigned short A[ROWCAP][128];
  __shared__ int rid[ROWCAP];
  __shared__ int rsegL[ROWCAP];
  __shared__ int offl[80];
  const int b = blockIdx.x;
  const int nf0 = nfA[b], nf1 = nfA[b+1];
  if (nf1 <= nf0) return;
  const int tid = threadIdx.x;
  int nseg = nf1 - nf0; if (nseg > 79) nseg = 79;
  const int rb = off[nf0];
  int rows = off[nf1] - rb;
  if (rows > ROWCAP) rows = ROWCAP;
  if (tid <= nseg) offl[tid] = off[nf0 + tid];
  {
    int c16 = tid & 15;
    #pragma unroll
    for (int p=0;p<6;++p){
      int i = p*16 + (tid>>4);
      int colsw = (c16*8) ^ ((i&7)<<3);
      if (i < rows){
        int e = sorted[rb + i];
        const float* pm = msg + (size_t)e*128 + c16*8;
        float4 v0 = *(const float4*)pm;
        float4 v1 = *(const float4*)(pm+4);
        *(uint4*)&A[i][colsw] = (uint4){pk2(v0.x,v0.y),pk2(v0.z,v0.w),pk2(v1.x,v1.y),pk2(v1.z,v1.w)};
        if (c16==0) rid[i] = e;
      } else {
        *(uint4*)&A[i][colsw] = (uint4){0,0,0,0};
      }
    }
  }
  __syncthreads();
  if (tid < rows){
    int gr = rb + tid, s = 0;
    while (offl[s+1] <= gr) ++s;
    rsegL[tid] = s;
  }
  __syncthreads();
  const int w = tid>>6, l = tid&63, lr = l&15, lg = l>>4;
  const int R = (rows + 15) >> 4;
  int rsg[6][4];
  #pragma unroll
  for (int rt=0;rt<6;++rt)
    #pragma unroll
    for (int j=0;j<4;++j){
      int row = rt*16 + lg*4 + j;
      rsg[rt][j] = (rt < R && row < rows) ? rsegL[row] : 1000;
    }
  #pragma unroll
  for (int t=0;t<2;++t){
    const int d = w*32 + t*16 + lr;
    float p[6][4];
    #pragma unroll
    for (int rt=0;rt<6;++rt)
      #pragma unroll
      for (int j=0;j<4;++j) p[rt][j] = 0.f;
    #pragma unroll
    for (int h2=0;h2<2;++h2){
      s16x8 bfA[4], bfB[4];
      #pragma unroll
      for (int ks=0;ks<4;++ks){
        bfA[ks] = *(const s16x8*)(WaB + ((size_t)((h2*2+0)*128 + d)*128 + ks*32 + lg*8));
        bfB[ks] = *(const s16x8*)(WaB + ((size_t)((h2*2+1)*128 + d)*128 + ks*32 + lg*8));
      }
      float evA[6][4], evB[6][4];
      #pragma unroll
      for (int rt=0;rt<6;++rt){
        if (rt < R){
          f32x4 accA = (f32x4){0.f,0.f,0.f,0.f};
          f32x4 accB = (f32x4){0.f,0.f,0.f,0.f};
          #pragma unroll
          for (int ks=0;ks<4;++ks){
            int row = rt*16 + lr;
            s16x8 af = *(const s16x8*)&A[row][(ks*32 + lg*8) ^ ((row&7)<<3)];
            accA = __builtin_amdgcn_mfma_f32_16x16x32_bf16(af, bfA[ks], accA, 0,0,0);
            accB = __builtin_amdgcn_mfma_f32_16x16x32_bf16(af, bfB[ks], accB, 0,0,0);
          }
          #pragma unroll
          for (int j=0;j<4;++j){ evA[rt][j] = EXP2(accA[j]); evB[rt][j] = EXP2(accB[j]); }
        } else {
          #pragma unroll
          for (int j=0;j<4;++j){ evA[rt][j] = 0.f; evB[rt][j] = 0.f; }
        }
      }
      for (int s=0; s<nseg; ++s){
        int a  = offl[s]   - rb;
        int b2 = offl[s+1] - rb; if (b2 > rows) b2 = rows;
        if (b2 <= a) continue;
        int rtlo = a >> 4, rthi = (b2-1) >> 4;
        float psA = 0.f, psB = 0.f;
        #pragma unroll
        for (int rt=0;rt<6;++rt){
          if (rt >= rtlo && rt <= rthi){
            #pragma unroll
            for (int j=0;j<4;++j){
              bool m = (rsg[rt][j]==s);
              psA += m ? evA[rt][j] : 0.f;
              psB += m ? evB[rt][j] : 0.f;
            }
          }
        }
        psA += __shfl_xor(psA, 16, 64);
        psA += __shfl_xor(psA, 32, 64);
        psB += __shfl_xor(psB, 16, 64);
        psB += __shfl_xor(psB, 32, 64);
        float ivA = __builtin_amdgcn_rcpf(4.0f*psA);   // 0.25 folded in
        float ivB = __builtin_amdgcn_rcpf(4.0f*psB);
        #pragma unroll
        for (int rt=0;rt<6;++rt){
          if (rt >= rtlo && rt <= rthi){
            #pragma unroll
            for (int j=0;j<4;++j){
              float add = evA[rt][j]*ivA + evB[rt][j]*ivB;
              p[rt][j] += (rsg[rt][j]==s) ? add : 0.f;
            }
          }
        }
      }
    }
    // m via identity-MFMA: m = A @ I (exact), f32 in C-layout; then phi = p*m (0.25 pre-folded)
    s16x8 idf[4];
    #pragma unroll
    for (int ks=0;ks<4;++ks){
      int tk = d - ks*32 - lg*8;   // in [0,8) iff this frag element equals column d
      short e8[8];
      #pragma unroll
      for (int i=0;i<8;++i) e8[i] = (i==tk) ? (short)0x3F80 : (short)0;
      idf[ks] = (s16x8){e8[0],e8[1],e8[2],e8[3],e8[4],e8[5],e8[6],e8[7]};
    }
    #pragma unroll
    for (int rt=0;rt<6;++rt){
      if (rt < R){
        f32x4 macc = (f32x4){0.f,0.f,0.f,0.f};
        #pragma unroll
        for (int ks=0;ks<4;++ks){
          int row = rt*16 + lr;
          s16x8 af = *(const s16x8*)&A[row][(ks*32 + lg*8) ^ ((row&7)<<3)];
          macc = __builtin_amdgcn_mfma_f32_16x16x32_bf16(af, idf[ks], macc, 0,0,0);
        }
        #pragma unroll
        for (int j=0;j<4;++j){
          int row = rt*16 + lg*4 + j;
          if (row < rows)
            phi[(size_t)rid[row]*128 + d] = f2b(p[rt][j] * macc[j]);
        }
      }
    }
  }
}

// ---------------- K3: fused gather(phi by tgt) + GRU, 16 nodes per block (grid 1250)
__global__ __launch_bounds__(256,4) void k_gg(const float* x, const unsigned short* xb,
                                              const unsigned short* phi,
                                              const int* off2, const int* sortedT,
                                              const unsigned short* WiB, const unsigned short* WhB,
                                              const float* bih, const float* bhh, float* emb){
  const int base = blockIdx.x*16;
  __shared__ unsigned short Ax[16][136];
  __shared__ unsigned short Ag[16][136];
  __shared__ float aggF[16][132];
  const int tid = threadIdx.x;
  {
    int i = tid>>4, q = tid&15;          // node i, 8-feature slice q
    int node = base + i;
    float acc[8];
    #pragma unroll
    for (int j=0;j<8;++j) acc[j]=0.f;
    int o0 = off2[node], o1 = off2[node+1];
    for (int o=o0; o<o1; ++o){
      int e = sortedT[o];
      uint4 u = *(const uint4*)(phi + (size_t)e*128 + q*8);
      acc[0] += b2f((unsigned short)(u.x & 0xffffu));
      acc[1] += b2f((unsigned short)(u.x >> 16));
      acc[2] += b2f((unsigned short)(u.y & 0xffffu));
      acc[3] += b2f((unsigned short)(u.y >> 16));
      acc[4] += b2f((unsigned short)(u.z & 0xffffu));
      acc[5] += b2f((unsigned short)(u.z >> 16));
      acc[6] += b2f((unsigned short)(u.w & 0xffffu));
      acc[7] += b2f((unsigned short)(u.w >> 16));
    }
    *(float4*)&aggF[i][q*8]   = (float4){acc[0],acc[1],acc[2],acc[3]};
    *(float4*)&aggF[i][q*8+4] = (float4){acc[4],acc[5],acc[6],acc[7]};
    *(uint4*)&Ag[i][q*8] = (uint4){pk2(acc[0],acc[1]),pk2(acc[2],acc[3]),
                                   pk2(acc[4],acc[5]),pk2(acc[6],acc[7])};
    *(uint4*)&Ax[i][q*8] = *(const uint4*)(xb + (size_t)node*128 + q*8);
  }
  __syncthreads();
  const int w = tid>>6, l = tid&63, lr = l&15, lg = l>>4;
  // A fragments: row = lr (16 rows), k = ks*32 + lg*8
  s16x8 ax[4], ag[4];
  #pragma unroll
  for (int ks=0;ks<4;++ks){
    ax[ks] = *(const s16x8*)&Ax[lr][ks*32+lg*8];
    ag[ks] = *(const s16x8*)&Ag[lr][ks*32+lg*8];
  }
  float rr[2][4], zz[2][4];
  #pragma unroll
  for (int c=0;c<3;++c){
    f32x4 aI[2], aH[2];
    #pragma unroll
    for (int i=0;i<2;++i){ aI[i]=(f32x4){0.f,0.f,0.f,0.f}; aH[i]=(f32x4){0.f,0.f,0.f,0.f}; }
    #pragma unroll
    for (int ks=0;ks<4;++ks){
      #pragma unroll
      for (int n2=0;n2<2;++n2){
        int col = w*32 + n2*16 + lr;
        s16x8 bI = *(const s16x8*)(WiB + ((c*128 + col)*128 + ks*32 + lg*8));
        s16x8 bH = *(const s16x8*)(WhB + ((c*128 + col)*128 + ks*32 + lg*8));
        aI[n2] = __builtin_amdgcn_mfma_f32_16x16x32_bf16(ax[ks], bI, aI[n2], 0,0,0);
        aH[n2] = __builtin_amdgcn_mfma_f32_16x16x32_bf16(ag[ks], bH, aH[n2], 0,0,0);
      }
    }
    #pragma unroll
    for (int n2=0;n2<2;++n2){
      int d = w*32 + n2*16 + lr;
      float bI = bih[c*128 + d];
      float bH = bhh[c*128 + d];
      #pragma unroll
      for (int j=0;j<4;++j){
        float gi = aI[n2][j] + bI;
        float gh = aH[n2][j] + bH;
        if (c==0){
          rr[n2][j] = sigm(gi + gh);
        } else if (c==1){
          zz[n2][j] = sigm(gi + gh);
        } else {
          float nn = tanhfast(gi + rr[n2][j]*gh);
          int irow = lg*4 + j;
          int node = base + irow;
          float a = aggF[irow][d];
          float z = zz[n2][j];
          emb[(size_t)node*128 + d] = (1.0f - z)*nn + z*a;
        }
      }
    }
  }
}

extern "C" void kernel_launch(void* const* d_in, const int* in_sizes, int n_in,
                              void* d_out, int out_size, void* d_ws, size_t ws_size,
                              hipStream_t stream){
  (void)in_sizes; (void)n_in; (void)out_size;
  const float* x    = (const float*)d_in[0];
  const int*   ei   = (const int*)d_in[1];
  const float* ea   = (const float*)d_in[2];
  const float* We   = (const float*)d_in[4];
  const float* Whu  = (const float*)d_in[5];
  const float* Whw  = (const float*)d_in[6];
  const float* Wa   = (const float*)d_in[7];
  const float* Wi   = (const float*)d_in[8];
  const float* Wh   = (const float*)d_in[9];
  const float* bih  = (const float*)d_in[10];
  const float* bhh  = (const float*)d_in[11];
  float* out = (float*)d_out;
  float* emb = out;
  float* msg = out + (size_t)N_NODES*128;

  if (ws_size < 90600000) return;
  char* ws = (char*)d_ws;
  unsigned short* phi     = (unsigned short*)(ws);                 // 81,920,000
  unsigned short* xb      = (unsigned short*)(ws + 81920000);      //  5,120,000
  unsigned short* WcatB   = (unsigned short*)(ws + 87040000);      //     98,304
  unsigned short* WaB     = (unsigned short*)(ws + 87138304);      //    131,072
  unsigned short* WiB     = (unsigned short*)(ws + 87269376);      //     98,304
  unsigned short* WhB     = (unsigned short*)(ws + 87367680);      //     98,304
  int*            cnt     = (int*)(ws + 87465984);                 //     80,000
  int*            cnt2    = (int*)(ws + 87545984);                 //     80,000 (adjacent to cnt)
  int*            off     = (int*)(ws + 87625984);                 //     80,016
  int*            off2    = (int*)(ws + 87706000);                 //     80,016
  int*            cursor  = (int*)(ws + 87786016);                 //     80,000
  int*            cursor2 = (int*)(ws + 87866016);                 //     80,000
  int*            sorted  = (int*)(ws + 87946016);                 //  1,280,000
  int*            sortedT = (int*)(ws + 89226016);                 //  1,280,000
  int*            nfA     = (int*)(ws + 90506016);                 //     26,672

  hipMemsetAsync(cnt, 0, 160000, stream);   // covers cnt + cnt2
  k_init<<<4582,256,0,stream>>>(We,Whu,Whw,Wa,Wi,Wh,WcatB,WaB,WiB,WhB, ei, cnt, cnt2, x, xb);
  k_scan<<<2,1024,0,stream>>>(cnt, cnt2, off, off2, cursor, cursor2);
  k_mid<<<1277,256,0,stream>>>(off, nfA, ei, cursor, cursor2, sorted, sortedT);
  k_messages<<<5000,256,0,stream>>>(ea, ei, xb, WcatB, msg);
  k_attn<<<NB2,256,0,stream>>>(msg, phi, WaB, off, sorted, nfA);
  k_gg<<<1250,256,0,stream>>>(x, xb, phi, off2, sortedT, WiB, WhB, bih, bhh, emb);
}

// Round 20
// 919.874 us; speedup vs baseline: 1.0011x; 1.0011x over previous
//
#include <hip/hip_runtime.h>

#define N_NODES 20000
#define N_EDGES 320000
#define EPB 48
#define NB2 6667              // ceil(N_EDGES/EPB)
#define ROWCAP 96

typedef __attribute__((ext_vector_type(4))) float f32x4;
typedef __attribute__((ext_vector_type(8))) short s16x8;

#define EXP2(x) exp2f(x)

// hardware RNE f32->bf16 (v_cvt_pk_bf16_f32): pair and scalar forms
__device__ __forceinline__ unsigned int pk2(float a, float b){
  unsigned int r;
  asm("v_cvt_pk_bf16_f32 %0, %1, %2" : "=v"(r) : "v"(a), "v"(b));
  return r;
}
__device__ __forceinline__ unsigned short f2b(float f){
  unsigned int r;
  asm("v_cvt_pk_bf16_f32 %0, %1, %1" : "=v"(r) : "v"(f));
  return (unsigned short)r;
}
__device__ __forceinline__ float b2f(unsigned short h){
  union { unsigned int u; float f; } v; v.u = ((unsigned int)h)<<16; return v.f;
}
__device__ __forceinline__ float sigm(float x){ return 1.0f/(1.0f+__expf(-x)); }
__device__ __forceinline__ float tanhfast(float x){ return 1.0f - 2.0f/(1.0f+__expf(2.0f*x)); }

// ---------------- fused: weight prep (0..831) + dual histogram (832..2081) + x->bf16 (2082..4581)
// WaB pre-scaled by log2(e) so k_attn uses exp2.
__global__ void k_init(const float* We, const float* Whu, const float* Whw,
                       const float* Wa, const float* Wi, const float* Wh,
                       unsigned short* WcatB, unsigned short* WaB,
                       unsigned short* WiB, unsigned short* WhB,
                       const int* ei, int* cnt, int* cnt2,
                       const float* x, unsigned short* xb){
  int b = blockIdx.x;
  if (b < 832){
    int i = b*256 + threadIdx.x;
    if (i < 49152){
      int d = i/384, k = i - d*384;
      float v = (k<128) ? We[d*128+k] : (k<256 ? Whu[d*128+k-128] : Whw[d*128+k-256]);
      WcatB[i] = f2b(v);
    } else if (i < 49152+65536){
      int j = i-49152; WaB[j] = f2b(Wa[j] * 1.4426950408889634f);
    } else if (i < 49152+65536+49152){
      int j = i-114688; WiB[j] = f2b(Wi[j]);
    } else if (i < 212992){
      int j = i-163840; WhB[j] = f2b(Wh[j]);
    }
  } else if (b < 2082){
    int e = (b-832)*256 + threadIdx.x;
    atomicAdd(&cnt[ei[e]], 1);
    atomicAdd(&cnt2[ei[N_EDGES + e]], 1);
  } else {
    int i = (b-2082)*256 + threadIdx.x;   // i in [0, 640000): one float4 each
    float4 v = *(const float4*)(x + (size_t)i*4);
    *(unsigned int*)(xb + (size_t)i*4)     = pk2(v.x, v.y);
    *(unsigned int*)(xb + (size_t)i*4 + 2) = pk2(v.z, v.w);
  }
}

// ---------------- scan: shfl-based
__global__ void k_scan(const int* cntA, const int* cntB, int* offA, int* offB,
                       int* curA, int* curB){
  const int* cnt = blockIdx.x ? cntB : cntA;
  int* off    = blockIdx.x ? offB : offA;
  int* cursor = blockIdx.x ? curB : curA;
  __shared__ int wsum[16];
  __shared__ int sbase;
  const int tid = threadIdx.x;
  const int wv = tid>>6, ln = tid&63;
  if (tid==0) sbase = 0;
  __syncthreads();
  for (int ch=0; ch<20; ++ch){
    int idx = ch*1024 + tid;
    int v = (idx < N_NODES) ? cnt[idx] : 0;
    int ps = v;
    #pragma unroll
    for (int s=1; s<64; s<<=1){
      int t = __shfl_up(ps, s, 64);
      if (ln >= s) ps += t;
    }
    if (ln==63) wsum[wv] = ps;
    __syncthreads();
    if (tid < 16){
      int wps = wsum[tid];
      #pragma unroll
      for (int s=1; s<16; s<<=1){
        int t = __shfl_up(wps, s, 64);
        if (tid >= s) wps += t;
      }
      wsum[tid] = wps;
    }
    __syncthreads();
    int base = sbase + (wv ? wsum[wv-1] : 0);
    int o = base + ps - v;
    if (idx < N_NODES){ off[idx] = o; cursor[idx] = o; }
    int total = wsum[15];
    __syncthreads();
    if (tid==0) sbase += total;
    __syncthreads();
  }
  if (tid==0) off[N_NODES] = sbase;
}

// ---------------- fused: blockmap (blocks 0..26) + dual scatter (27..1276)
__global__ void k_mid(const int* off, int* nfA, const int* ei,
                      int* cursor, int* cursor2, int* sorted, int* sortedT){
  int b = blockIdx.x;
  if (b < 27){
    int i = b*256 + threadIdx.x;
    if (i > NB2) return;
    int target = i*EPB;
    int lo = 0, hi = N_NODES;
    while (lo < hi){
      int mid = (lo + hi) >> 1;
      if (off[mid] < target) lo = mid + 1; else hi = mid;
    }
    nfA[i] = lo;
  } else {
    int e = (b-27)*256 + threadIdx.x;
    int s = ei[e];
    int t = ei[N_EDGES + e];
    int slot = atomicAdd(&cursor[s], 1);
    sorted[slot] = e;
    int slot2 = atomicAdd(&cursor2[t], 1);
    sortedT[slot2] = e;
  }
}

// ---------------- K1 (r13 form + xb gathers): messages = leaky(cat(ea,x[s],x[t]) @ Wcat^T)
__global__ __launch_bounds__(256,3) void k_messages(const float* ea, const int* ei,
                                                    const unsigned short* xb,
                                                    const unsigned short* WcatB,
                                                    float* msg_out){
  const int tid = threadIdx.x;
  const int e0 = blockIdx.x*64;
  __shared__ unsigned short A[64][392];
  const int w = tid>>6, l = tid&63, lr = l&15, lg = l>>4;
  s16x8 bfr[2][12];
  #pragma unroll
  for (int nt2=0; nt2<2; ++nt2){
    int colr = w*32 + nt2*16 + lr;
    #pragma unroll
    for (int ks=0; ks<12; ++ks)
      bfr[nt2][ks] = *(const s16x8*)(WcatB + colr*384 + ks*32 + lg*8);
  }
  {
    int i = tid>>2, q = tid&3;
    int e = e0 + i;
    int s = ei[e]; int t = ei[N_EDGES + e];
    const float* pe = ea + (size_t)e*128 + q*32;
    const unsigned short* ps = xb + (size_t)s*128 + q*32;
    const unsigned short* pt = xb + (size_t)t*128 + q*32;
    #pragma unroll
    for (int j=0;j<32;j+=8){
      float4 v0 = *(const float4*)(pe+j), v1 = *(const float4*)(pe+j+4);
      *(uint4*)&A[i][q*32+j] = (uint4){pk2(v0.x,v0.y),pk2(v0.z,v0.w),pk2(v1.x,v1.y),pk2(v1.z,v1.w)};
      *(uint4*)&A[i][128+q*32+j] = *(const uint4*)(ps+j);
      *(uint4*)&A[i][256+q*32+j] = *(const uint4*)(pt+j);
    }
  }
  __syncthreads();
  f32x4 acc[4][2];
  #pragma unroll
  for (int rt=0;rt<4;++rt)
    #pragma unroll
    for (int n2=0;n2<2;++n2) acc[rt][n2] = (f32x4){0.f,0.f,0.f,0.f};
  for (int ks=0; ks<12; ++ks){
    #pragma unroll
    for (int rt=0;rt<4;++rt){
      s16x8 af = *(const s16x8*)&A[rt*16 + lr][ks*32 + lg*8];
      acc[rt][0] = __builtin_amdgcn_mfma_f32_16x16x32_bf16(af, bfr[0][ks], acc[rt][0], 0,0,0);
      acc[rt][1] = __builtin_amdgcn_mfma_f32_16x16x32_bf16(af, bfr[1][ks], acc[rt][1], 0,0,0);
    }
  }
  #pragma unroll
  for (int rt=0;rt<4;++rt){
    #pragma unroll
    for (int n2=0;n2<2;++n2){
      int col = w*32 + n2*16 + lr;
      #pragma unroll
      for (int j=0;j<4;++j){
        int row = e0 + rt*16 + lg*4 + j;
        float v = acc[rt][n2][j];
        v = (v>0.f) ? v : 0.01f*v;
        msg_out[(size_t)row*128 + col] = v;
      }
    }
  }
}

// ---------------- K2: r16 form + h-pair-fused segment reduce (shared masks/control)
__global__ __launch_bounds__(256,5) void k_attn(const float* msg, unsigned short* phi,
                                                const unsigned short* WaB,
                                                const int* off, const int* sorted, const int* nfA){
  __shared__ unsigned short A[ROWCAP][128];
  __shared__ int rid[ROWCAP];
  __shared__ int rsegL[ROWCAP];
  __shared__ int offl[80];
  const int b = blockIdx.x;
  const int nf0 = nfA[b], nf1 = nfA[b+1];
  if (nf1 <= nf0) return;
  const int tid = threadIdx.x;
  int nseg = nf1 - nf0; if (nseg > 79) nseg = 79;
  const int rb = off[nf0];
  int rows = off[nf1] - rb;
  if (rows > ROWCAP) rows = ROWCAP;
  if (tid <= nseg) offl[tid] = off[nf0 + tid];
  {
    int c16 = tid & 15;
    #pragma unroll
    for (int p=0;p<6;++p){
      int i = p*16 + (tid>>4);
      int colsw = (c16*8) ^ ((i&7)<<3);
      if (i < rows){
        int e = sorted[rb + i];
        const float* pm = msg + (size_t)e*128 + c16*8;
        float4 v0 = *(const float4*)pm;
        float4 v1 = *(const float4*)(pm+4);
        *(uint4*)&A[i][colsw] = (uint4){pk2(v0.x,v0.y),pk2(v0.z,v0.w),pk2(v1.x,v1.y),pk2(v1.z,v1.w)};
        if (c16==0) rid[i] = e;
      } else {
        *(uint4*)&A[i][colsw] = (uint4){0,0,0,0};
      }
    }
  }
  __syncthreads();
  if (tid < rows){
    int gr = rb + tid, s = 0;
    while (offl[s+1] <= gr) ++s;
    rsegL[tid] = s;
  }
  __syncthreads();
  const int w = tid>>6, l = tid&63, lr = l&15, lg = l>>4;
  const int R = (rows + 15) >> 4;
  int rsg[6][4];
  #pragma unroll
  for (int rt=0;rt<6;++rt)
    #pragma unroll
    for (int j=0;j<4;++j){
      int row = rt*16 + lg*4 + j;
      rsg[rt][j] = (rt < R && row < rows) ? rsegL[row] : 1000;
    }
  #pragma unroll
  for (int t=0;t<2;++t){
    const int d = w*32 + t*16 + lr;
    float p[6][4];
    #pragma unroll
    for (int rt=0;rt<6;++rt)
      #pragma unroll
      for (int j=0;j<4;++j) p[rt][j] = 0.f;
    #pragma unroll
    for (int h2=0;h2<2;++h2){
      s16x8 bfA[4], bfB[4];
      #pragma unroll
      for (int ks=0;ks<4;++ks){
        bfA[ks] = *(const s16x8*)(WaB + ((size_t)((h2*2+0)*128 + d)*128 + ks*32 + lg*8));
        bfB[ks] = *(const s16x8*)(WaB + ((size_t)((h2*2+1)*128 + d)*128 + ks*32 + lg*8));
      }
      float evA[6][4], evB[6][4];
      #pragma unroll
      for (int rt=0;rt<6;++rt){
        if (rt < R){
          f32x4 accA = (f32x4){0.f,0.f,0.f,0.f};
          f32x4 accB = (f32x4){0.f,0.f,0.f,0.f};
          #pragma unroll
          for (int ks=0;ks<4;++ks){
            int row = rt*16 + lr;
            s16x8 af = *(const s16x8*)&A[row][(ks*32 + lg*8) ^ ((row&7)<<3)];
            accA = __builtin_amdgcn_mfma_f32_16x16x32_bf16(af, bfA[ks], accA, 0,0,0);
            accB = __builtin_amdgcn_mfma_f32_16x16x32_bf16(af, bfB[ks], accB, 0,0,0);
          }
          #pragma unroll
          for (int j=0;j<4;++j){ evA[rt][j] = EXP2(accA[j]); evB[rt][j] = EXP2(accB[j]); }
        } else {
          #pragma unroll
          for (int j=0;j<4;++j){ evA[rt][j] = 0.f; evB[rt][j] = 0.f; }
        }
      }
      for (int s=0; s<nseg; ++s){
        int a  = offl[s]   - rb;
        int b2 = offl[s+1] - rb; if (b2 > rows) b2 = rows;
        if (b2 <= a) continue;
        int rtlo = a >> 4, rthi = (b2-1) >> 4;
        float psA = 0.f, psB = 0.f;
        #pragma unroll
        for (int rt=0;rt<6;++rt){
          if (rt >= rtlo && rt <= rthi){
            #pragma unroll
            for (int j=0;j<4;++j){
              bool m = (rsg[rt][j]==s);
              psA += m ? evA[rt][j] : 0.f;
              psB += m ? evB[rt][j] : 0.f;
            }
          }
        }
        psA += __shfl_xor(psA, 16, 64);
        psA += __shfl_xor(psA, 32, 64);
        psB += __shfl_xor(psB, 16, 64);
        psB += __shfl_xor(psB, 32, 64);
        float ivA = __builtin_amdgcn_rcpf(4.0f*psA);   // 0.25 folded in
        float ivB = __builtin_amdgcn_rcpf(4.0f*psB);
        #pragma unroll
        for (int rt=0;rt<6;++rt){
          if (rt >= rtlo && rt <= rthi){
            #pragma unroll
            for (int j=0;j<4;++j){
              float add = evA[rt][j]*ivA + evB[rt][j]*ivB;
              p[rt][j] += (rsg[rt][j]==s) ? add : 0.f;
            }
          }
        }
      }
    }
    // m via identity-MFMA: m = A @ I (exact), f32 in C-layout; then phi = p*m (0.25 pre-folded)
    s16x8 idf[4];
    #pragma unroll
    for (int ks=0;ks<4;++ks){
      int tk = d - ks*32 - lg*8;   // in [0,8) iff this frag element equals column d
      short e8[8];
      #pragma unroll
      for (int i=0;i<8;++i) e8[i] = (i==tk) ? (short)0x3F80 : (short)0;
      idf[ks] = (s16x8){e8[0],e8[1],e8[2],e8[3],e8[4],e8[5],e8[6],e8[7]};
    }
    #pragma unroll
    for (int rt=0;rt<6;++rt){
      if (rt < R){
        f32x4 macc = (f32x4){0.f,0.f,0.f,0.f};
        #pragma unroll
        for (int ks=0;ks<4;++ks){
          int row = rt*16 + lr;
          s16x8 af = *(const s16x8*)&A[row][(ks*32 + lg*8) ^ ((row&7)<<3)];
          macc = __builtin_amdgcn_mfma_f32_16x16x32_bf16(af, idf[ks], macc, 0,0,0);
        }
        #pragma unroll
        for (int j=0;j<4;++j){
          int row = rt*16 + lg*4 + j;
          if (row < rows)
            phi[(size_t)rid[row]*128 + d] = f2b(p[rt][j] * macc[j]);
        }
      }
    }
  }
}

// ---------------- K3: fused gather(phi by tgt) + GRU, 16 nodes per block (grid 1250)
__global__ __launch_bounds__(256,4) void k_gg(const float* x, const unsigned short* xb,
                                              const unsigned short* phi,
                                              const int* off2, const int* sortedT,
                                              const unsigned short* WiB, const unsigned short* WhB,
                                              const float* bih, const float* bhh, float* emb){
  const int base = blockIdx.x*16;
  __shared__ unsigned short Ax[16][136];
  __shared__ unsigned short Ag[16][136];
  __shared__ float aggF[16][132];
  const int tid = threadIdx.x;
  {
    int i = tid>>4, q = tid&15;          // node i, 8-feature slice q
    int node = base + i;
    float acc[8];
    #pragma unroll
    for (int j=0;j<8;++j) acc[j]=0.f;
    int o0 = off2[node], o1 = off2[node+1];
    for (int o=o0; o<o1; ++o){
      int e = sortedT[o];
      uint4 u = *(const uint4*)(phi + (size_t)e*128 + q*8);
      acc[0] += b2f((unsigned short)(u.x & 0xffffu));
      acc[1] += b2f((unsigned short)(u.x >> 16));
      acc[2] += b2f((unsigned short)(u.y & 0xffffu));
      acc[3] += b2f((unsigned short)(u.y >> 16));
      acc[4] += b2f((unsigned short)(u.z & 0xffffu));
      acc[5] += b2f((unsigned short)(u.z >> 16));
      acc[6] += b2f((unsigned short)(u.w & 0xffffu));
      acc[7] += b2f((unsigned short)(u.w >> 16));
    }
    *(float4*)&aggF[i][q*8]   = (float4){acc[0],acc[1],acc[2],acc[3]};
    *(float4*)&aggF[i][q*8+4] = (float4){acc[4],acc[5],acc[6],acc[7]};
    *(uint4*)&Ag[i][q*8] = (uint4){pk2(acc[0],acc[1]),pk2(acc[2],acc[3]),
                                   pk2(acc[4],acc[5]),pk2(acc[6],acc[7])};
    *(uint4*)&Ax[i][q*8] = *(const uint4*)(xb + (size_t)node*128 + q*8);
  }
  __syncthreads();
  const int w = tid>>6, l = tid&63, lr = l&15, lg = l>>4;
  // A fragments: row = lr (16 rows), k = ks*32 + lg*8
  s16x8 ax[4], ag[4];
  #pragma unroll
  for (int ks=0;ks<4;++ks){
    ax[ks] = *(const s16x8*)&Ax[lr][ks*32+lg*8];
    ag[ks] = *(const s16x8*)&Ag[lr][ks*32+lg*8];
  }
  float rr[2][4], zz[2][4];
  #pragma unroll
  for (int c=0;c<3;++c){
    f32x4 aI[2], aH[2];
    #pragma unroll
    for (int i=0;i<2;++i){ aI[i]=(f32x4){0.f,0.f,0.f,0.f}; aH[i]=(f32x4){0.f,0.f,0.f,0.f}; }
    #pragma unroll
    for (int ks=0;ks<4;++ks){
      #pragma unroll
      for (int n2=0;n2<2;++n2){
        int col = w*32 + n2*16 + lr;
        s16x8 bI = *(const s16x8*)(WiB + ((c*128 + col)*128 + ks*32 + lg*8));
        s16x8 bH = *(const s16x8*)(WhB + ((c*128 + col)*128 + ks*32 + lg*8));
        aI[n2] = __builtin_amdgcn_mfma_f32_16x16x32_bf16(ax[ks], bI, aI[n2], 0,0,0);
        aH[n2] = __builtin_amdgcn_mfma_f32_16x16x32_bf16(ag[ks], bH, aH[n2], 0,0,0);
      }
    }
    #pragma unroll
    for (int n2=0;n2<2;++n2){
      int d = w*32 + n2*16 + lr;
      float bI = bih[c*128 + d];
      float bH = bhh[c*128 + d];
      #pragma unroll
      for (int j=0;j<4;++j){
        float gi = aI[n2][j] + bI;
        float gh = aH[n2][j] + bH;
        if (c==0){
          rr[n2][j] = sigm(gi + gh);
        } else if (c==1){
          zz[n2][j] = sigm(gi + gh);
        } else {
          float nn = tanhfast(gi + rr[n2][j]*gh);
          int irow = lg*4 + j;
          int node = base + irow;
          float a = aggF[irow][d];
          float z = zz[n2][j];
          emb[(size_t)node*128 + d] = (1.0f - z)*nn + z*a;
        }
      }
    }
  }
}

extern "C" void kernel_launch(void* const* d_in, const int* in_sizes, int n_in,
                              void* d_out, int out_size, void* d_ws, size_t ws_size,
                              hipStream_t stream){
  (void)in_sizes; (void)n_in; (void)out_size;
  const float* x    = (const float*)d_in[0];
  const int*   ei   = (const int*)d_in[1];
  const float* ea   = (const float*)d_in[2];
  const float* We   = (const float*)d_in[4];
  const float* Whu  = (const float*)d_in[5];
  const float* Whw  = (const float*)d_in[6];
  const float* Wa   = (const float*)d_in[7];
  const float* Wi   = (const float*)d_in[8];
  const float* Wh   = (const float*)d_in[9];
  const float* bih  = (const float*)d_in[10];
  const float* bhh  = (const float*)d_in[11];
  float* out = (float*)d_out;
  float* emb = out;
  float* msg = out + (size_t)N_NODES*128;

  if (ws_size < 90600000) return;
  char* ws = (char*)d_ws;
  unsigned short* phi     = (unsigned short*)(ws);                 // 81,920,000
  unsigned short* xb      = (unsigned short*)(ws + 81920000);      //  5,120,000
  unsigned short* WcatB   = (unsigned short*)(ws + 87040000);      //     98,304
  unsigned short* WaB     = (unsigned short*)(ws + 87138304);      //    131,072
  unsigned short* WiB     = (unsigned short*)(ws + 87269376);      //     98,304
  unsigned short* WhB     = (unsigned short*)(ws + 87367680);      //     98,304
  int*            cnt     = (int*)(ws + 87465984);                 //     80,000
  int*            cnt2    = (int*)(ws + 87545984);                 //     80,000 (adjacent to cnt)
  int*            off     = (int*)(ws + 87625984);                 //     80,016
  int*            off2    = (int*)(ws + 87706000);                 //     80,016
  int*            cursor  = (int*)(ws + 87786016);                 //     80,000
  int*            cursor2 = (int*)(ws + 87866016);                 //     80,000
  int*            sorted  = (int*)(ws + 87946016);                 //  1,280,000
  int*            sortedT = (int*)(ws + 89226016);                 //  1,280,000
  int*            nfA     = (int*)(ws + 90506016);                 //     26,672

  hipMemsetAsync(cnt, 0, 160000, stream);   // covers cnt + cnt2
  k_init<<<4582,256,0,stream>>>(We,Whu,Whw,Wa,Wi,Wh,WcatB,WaB,WiB,WhB, ei, cnt, cnt2, x, xb);
  k_scan<<<2,1024,0,stream>>>(cnt, cnt2, off, off2, cursor, cursor2);
  k_mid<<<1277,256,0,stream>>>(off, nfA, ei, cursor, cursor2, sorted, sortedT);
  k_messages<<<5000,256,0,stream>>>(ea, ei, xb, WcatB, msg);
  k_attn<<<NB2,256,0,stream>>>(msg, phi, WaB, off, sorted, nfA);
  k_gg<<<1250,256,0,stream>>>(x, xb, phi, off2, sortedT, WiB, WhB, bih, bhh, emb);
}

// Round 21
// 481.742 us; speedup vs baseline: 1.9117x; 1.9095x over previous
//
#include <hip/hip_runtime.h>

#define N_NODES 20000
#define N_EDGES 320000
#define EPB 48
#define NB2 6667              // ceil(N_EDGES/EPB)
#define ROWCAP 96

typedef __attribute__((ext_vector_type(4))) float f32x4;
typedef __attribute__((ext_vector_type(8))) short s16x8;

#define EXP2(x) exp2f(x)

// hardware RNE f32->bf16 (v_cvt_pk_bf16_f32): pair and scalar forms
__device__ __forceinline__ unsigned int pk2(float a, float b){
  unsigned int r;
  asm("v_cvt_pk_bf16_f32 %0, %1, %2" : "=v"(r) : "v"(a), "v"(b));
  return r;
}
__device__ __forceinline__ unsigned short f2b(float f){
  unsigned int r;
  asm("v_cvt_pk_bf16_f32 %0, %1, %1" : "=v"(r) : "v"(f));
  return (unsigned short)r;
}
__device__ __forceinline__ float b2f(unsigned short h){
  union { unsigned int u; float f; } v; v.u = ((unsigned int)h)<<16; return v.f;
}
__device__ __forceinline__ float sigm(float x){ return 1.0f/(1.0f+__expf(-x)); }
__device__ __forceinline__ float tanhfast(float x){ return 1.0f - 2.0f/(1.0f+__expf(2.0f*x)); }

// ---------------- fused: weight prep (0..831) + dual histogram (832..2081) + x->bf16 (2082..4581)
// WaB pre-scaled by log2(e) so k_attn uses exp2.
__global__ void k_init(const float* We, const float* Whu, const float* Whw,
                       const float* Wa, const float* Wi, const float* Wh,
                       unsigned short* WcatB, unsigned short* WaB,
                       unsigned short* WiB, unsigned short* WhB,
                       const int* ei, int* cnt, int* cnt2,
                       const float* x, unsigned short* xb){
  int b = blockIdx.x;
  if (b < 832){
    int i = b*256 + threadIdx.x;
    if (i < 49152){
      int d = i/384, k = i - d*384;
      float v = (k<128) ? We[d*128+k] : (k<256 ? Whu[d*128+k-128] : Whw[d*128+k-256]);
      WcatB[i] = f2b(v);
    } else if (i < 49152+65536){
      int j = i-49152; WaB[j] = f2b(Wa[j] * 1.4426950408889634f);
    } else if (i < 49152+65536+49152){
      int j = i-114688; WiB[j] = f2b(Wi[j]);
    } else if (i < 212992){
      int j = i-163840; WhB[j] = f2b(Wh[j]);
    }
  } else if (b < 2082){
    int e = (b-832)*256 + threadIdx.x;
    atomicAdd(&cnt[ei[e]], 1);
    atomicAdd(&cnt2[ei[N_EDGES + e]], 1);
  } else {
    int i = (b-2082)*256 + threadIdx.x;   // i in [0, 640000): one float4 each
    float4 v = *(const float4*)(x + (size_t)i*4);
    *(unsigned int*)(xb + (size_t)i*4)     = pk2(v.x, v.y);
    *(unsigned int*)(xb + (size_t)i*4 + 2) = pk2(v.z, v.w);
  }
}

// ---------------- scan: shfl-based
__global__ void k_scan(const int* cntA, const int* cntB, int* offA, int* offB,
                       int* curA, int* curB){
  const int* cnt = blockIdx.x ? cntB : cntA;
  int* off    = blockIdx.x ? offB : offA;
  int* cursor = blockIdx.x ? curB : curA;
  __shared__ int wsum[16];
  __shared__ int sbase;
  const int tid = threadIdx.x;
  const int wv = tid>>6, ln = tid&63;
  if (tid==0) sbase = 0;
  __syncthreads();
  for (int ch=0; ch<20; ++ch){
    int idx = ch*1024 + tid;
    int v = (idx < N_NODES) ? cnt[idx] : 0;
    int ps = v;
    #pragma unroll
    for (int s=1; s<64; s<<=1){
      int t = __shfl_up(ps, s, 64);
      if (ln >= s) ps += t;
    }
    if (ln==63) wsum[wv] = ps;
    __syncthreads();
    if (tid < 16){
      int wps = wsum[tid];
      #pragma unroll
      for (int s=1; s<16; s<<=1){
        int t = __shfl_up(wps, s, 64);
        if (tid >= s) wps += t;
      }
      wsum[tid] = wps;
    }
    __syncthreads();
    int base = sbase + (wv ? wsum[wv-1] : 0);
    int o = base + ps - v;
    if (idx < N_NODES){ off[idx] = o; cursor[idx] = o; }
    int total = wsum[15];
    __syncthreads();
    if (tid==0) sbase += total;
    __syncthreads();
  }
  if (tid==0) off[N_NODES] = sbase;
}

// ---------------- fused: blockmap (blocks 0..26) + dual scatter (27..1276)
__global__ void k_mid(const int* off, int* nfA, const int* ei,
                      int* cursor, int* cursor2, int* sorted, int* sortedT){
  int b = blockIdx.x;
  if (b < 27){
    int i = b*256 + threadIdx.x;
    if (i > NB2) return;
    int target = i*EPB;
    int lo = 0, hi = N_NODES;
    while (lo < hi){
      int mid = (lo + hi) >> 1;
      if (off[mid] < target) lo = mid + 1; else hi = mid;
    }
    nfA[i] = lo;
  } else {
    int e = (b-27)*256 + threadIdx.x;
    int s = ei[e];
    int t = ei[N_EDGES + e];
    int slot = atomicAdd(&cursor[s], 1);
    sorted[slot] = e;
    int slot2 = atomicAdd(&cursor2[t], 1);
    sortedT[slot2] = e;
  }
}

// ---------------- K1 (r13 form + xb gathers): messages = leaky(cat(ea,x[s],x[t]) @ Wcat^T)
__global__ __launch_bounds__(256,3) void k_messages(const float* ea, const int* ei,
                                                    const unsigned short* xb,
                                                    const unsigned short* WcatB,
                                                    float* msg_out){
  const int tid = threadIdx.x;
  const int e0 = blockIdx.x*64;
  __shared__ unsigned short A[64][392];
  const int w = tid>>6, l = tid&63, lr = l&15, lg = l>>4;
  s16x8 bfr[2][12];
  #pragma unroll
  for (int nt2=0; nt2<2; ++nt2){
    int colr = w*32 + nt2*16 + lr;
    #pragma unroll
    for (int ks=0; ks<12; ++ks)
      bfr[nt2][ks] = *(const s16x8*)(WcatB + colr*384 + ks*32 + lg*8);
  }
  {
    int i = tid>>2, q = tid&3;
    int e = e0 + i;
    int s = ei[e]; int t = ei[N_EDGES + e];
    const float* pe = ea + (size_t)e*128 + q*32;
    const unsigned short* ps = xb + (size_t)s*128 + q*32;
    const unsigned short* pt = xb + (size_t)t*128 + q*32;
    #pragma unroll
    for (int j=0;j<32;j+=8){
      float4 v0 = *(const float4*)(pe+j), v1 = *(const float4*)(pe+j+4);
      *(uint4*)&A[i][q*32+j] = (uint4){pk2(v0.x,v0.y),pk2(v0.z,v0.w),pk2(v1.x,v1.y),pk2(v1.z,v1.w)};
      *(uint4*)&A[i][128+q*32+j] = *(const uint4*)(ps+j);
      *(uint4*)&A[i][256+q*32+j] = *(const uint4*)(pt+j);
    }
  }
  __syncthreads();
  f32x4 acc[4][2];
  #pragma unroll
  for (int rt=0;rt<4;++rt)
    #pragma unroll
    for (int n2=0;n2<2;++n2) acc[rt][n2] = (f32x4){0.f,0.f,0.f,0.f};
  for (int ks=0; ks<12; ++ks){
    #pragma unroll
    for (int rt=0;rt<4;++rt){
      s16x8 af = *(const s16x8*)&A[rt*16 + lr][ks*32 + lg*8];
      acc[rt][0] = __builtin_amdgcn_mfma_f32_16x16x32_bf16(af, bfr[0][ks], acc[rt][0], 0,0,0);
      acc[rt][1] = __builtin_amdgcn_mfma_f32_16x16x32_bf16(af, bfr[1][ks], acc[rt][1], 0,0,0);
    }
  }
  #pragma unroll
  for (int rt=0;rt<4;++rt){
    #pragma unroll
    for (int n2=0;n2<2;++n2){
      int col = w*32 + n2*16 + lr;
      #pragma unroll
      for (int j=0;j<4;++j){
        int row = e0 + rt*16 + lg*4 + j;
        float v = acc[rt][n2][j];
        v = (v>0.f) ? v : 0.01f*v;
        msg_out[(size_t)row*128 + col] = v;
      }
    }
  }
}

// ---------------- K2 (r10 proven form, bounds 5): stages from msg f32; segment-
// range-restricted reduce; m via identity-MFMA; phi to its own buffer.
__global__ __launch_bounds__(256,5) void k_attn(const float* msg, unsigned short* phi,
                                                const unsigned short* WaB,
                                                const int* off, const int* sorted, const int* nfA){
  __shared__ unsigned short A[ROWCAP][128];
  __shared__ int rid[ROWCAP];
  __shared__ int rsegL[ROWCAP];
  __shared__ int offl[80];
  const int b = blockIdx.x;
  const int nf0 = nfA[b], nf1 = nfA[b+1];
  if (nf1 <= nf0) return;
  const int tid = threadIdx.x;
  int nseg = nf1 - nf0; if (nseg > 79) nseg = 79;
  const int rb = off[nf0];
  int rows = off[nf1] - rb;
  if (rows > ROWCAP) rows = ROWCAP;
  if (tid <= nseg) offl[tid] = off[nf0 + tid];
  {
    int c16 = tid & 15;
    #pragma unroll
    for (int p=0;p<6;++p){
      int i = p*16 + (tid>>4);
      int colsw = (c16*8) ^ ((i&7)<<3);
      if (i < rows){
        int e = sorted[rb + i];
        const float* pm = msg + (size_t)e*128 + c16*8;
        float4 v0 = *(const float4*)pm;
        float4 v1 = *(const float4*)(pm+4);
        *(uint4*)&A[i][colsw] = (uint4){pk2(v0.x,v0.y),pk2(v0.z,v0.w),pk2(v1.x,v1.y),pk2(v1.z,v1.w)};
        if (c16==0) rid[i] = e;
      } else {
        *(uint4*)&A[i][colsw] = (uint4){0,0,0,0};
      }
    }
  }
  __syncthreads();
  if (tid < rows){
    int gr = rb + tid, s = 0;
    while (offl[s+1] <= gr) ++s;
    rsegL[tid] = s;
  }
  __syncthreads();
  const int w = tid>>6, l = tid&63, lr = l&15, lg = l>>4;
  const int R = (rows + 15) >> 4;
  int rsg[6][4];
  #pragma unroll
  for (int rt=0;rt<6;++rt)
    #pragma unroll
    for (int j=0;j<4;++j){
      int row = rt*16 + lg*4 + j;
      rsg[rt][j] = (rt < R && row < rows) ? rsegL[row] : 1000;
    }
  #pragma unroll
  for (int t=0;t<2;++t){
    const int d = w*32 + t*16 + lr;
    float p[6][4];
    #pragma unroll
    for (int rt=0;rt<6;++rt)
      #pragma unroll
      for (int j=0;j<4;++j) p[rt][j] = 0.f;
    #pragma unroll
    for (int h=0;h<4;++h){
      s16x8 bf[4];
      #pragma unroll
      for (int ks=0;ks<4;++ks)
        bf[ks] = *(const s16x8*)(WaB + ((size_t)(h*128 + d)*128 + ks*32 + lg*8));
      float ev[6][4];
      #pragma unroll
      for (int rt=0;rt<6;++rt){
        if (rt < R){
          f32x4 acc = (f32x4){0.f,0.f,0.f,0.f};
          #pragma unroll
          for (int ks=0;ks<4;++ks){
            int row = rt*16 + lr;
            s16x8 af = *(const s16x8*)&A[row][(ks*32 + lg*8) ^ ((row&7)<<3)];
            acc = __builtin_amdgcn_mfma_f32_16x16x32_bf16(af, bf[ks], acc, 0,0,0);
          }
          #pragma unroll
          for (int j=0;j<4;++j) ev[rt][j] = EXP2(acc[j]);
        } else {
          #pragma unroll
          for (int j=0;j<4;++j) ev[rt][j] = 0.f;
        }
      }
      for (int s=0; s<nseg; ++s){
        int a  = offl[s]   - rb;
        int b2 = offl[s+1] - rb; if (b2 > rows) b2 = rows;
        if (b2 <= a) continue;
        int rtlo = a >> 4, rthi = (b2-1) >> 4;
        float ps = 0.f;
        #pragma unroll
        for (int rt=0;rt<6;++rt){
          if (rt >= rtlo && rt <= rthi){
            #pragma unroll
            for (int j=0;j<4;++j)
              ps += (rsg[rt][j]==s) ? ev[rt][j] : 0.f;
          }
        }
        ps += __shfl_xor(ps, 16, 64);
        ps += __shfl_xor(ps, 32, 64);
        float iv = __builtin_amdgcn_rcpf(4.0f*ps);   // 0.25 folded in
        #pragma unroll
        for (int rt=0;rt<6;++rt){
          if (rt >= rtlo && rt <= rthi){
            #pragma unroll
            for (int j=0;j<4;++j)
              p[rt][j] += (rsg[rt][j]==s) ? ev[rt][j]*iv : 0.f;
          }
        }
      }
    }
    // m via identity-MFMA: m = A @ I (exact), f32 in C-layout; then phi = p*m (0.25 pre-folded)
    s16x8 idf[4];
    #pragma unroll
    for (int ks=0;ks<4;++ks){
      int tk = d - ks*32 - lg*8;   // in [0,8) iff this frag element equals column d
      short e8[8];
      #pragma unroll
      for (int i=0;i<8;++i) e8[i] = (i==tk) ? (short)0x3F80 : (short)0;
      idf[ks] = (s16x8){e8[0],e8[1],e8[2],e8[3],e8[4],e8[5],e8[6],e8[7]};
    }
    #pragma unroll
    for (int rt=0;rt<6;++rt){
      if (rt < R){
        f32x4 macc = (f32x4){0.f,0.f,0.f,0.f};
        #pragma unroll
        for (int ks=0;ks<4;++ks){
          int row = rt*16 + lr;
          s16x8 af = *(const s16x8*)&A[row][(ks*32 + lg*8) ^ ((row&7)<<3)];
          macc = __builtin_amdgcn_mfma_f32_16x16x32_bf16(af, idf[ks], macc, 0,0,0);
        }
        #pragma unroll
        for (int j=0;j<4;++j){
          int row = rt*16 + lg*4 + j;
          if (row < rows)
            phi[(size_t)rid[row]*128 + d] = f2b(p[rt][j] * macc[j]);
        }
      }
    }
  }
}

// ---------------- K3: fused gather(phi by tgt) + GRU, 16 nodes per block (grid 1250)
__global__ __launch_bounds__(256,4) void k_gg(const float* x, const unsigned short* xb,
                                              const unsigned short* phi,
                                              const int* off2, const int* sortedT,
                                              const unsigned short* WiB, const unsigned short* WhB,
                                              const float* bih, const float* bhh, float* emb){
  const int base = blockIdx.x*16;
  __shared__ unsigned short Ax[16][136];
  __shared__ unsigned short Ag[16][136];
  __shared__ float aggF[16][132];
  const int tid = threadIdx.x;
  {
    int i = tid>>4, q = tid&15;          // node i, 8-feature slice q
    int node = base + i;
    float acc[8];
    #pragma unroll
    for (int j=0;j<8;++j) acc[j]=0.f;
    int o0 = off2[node], o1 = off2[node+1];
    for (int o=o0; o<o1; ++o){
      int e = sortedT[o];
      uint4 u = *(const uint4*)(phi + (size_t)e*128 + q*8);
      acc[0] += b2f((unsigned short)(u.x & 0xffffu));
      acc[1] += b2f((unsigned short)(u.x >> 16));
      acc[2] += b2f((unsigned short)(u.y & 0xffffu));
      acc[3] += b2f((unsigned short)(u.y >> 16));
      acc[4] += b2f((unsigned short)(u.z & 0xffffu));
      acc[5] += b2f((unsigned short)(u.z >> 16));
      acc[6] += b2f((unsigned short)(u.w & 0xffffu));
      acc[7] += b2f((unsigned short)(u.w >> 16));
    }
    *(float4*)&aggF[i][q*8]   = (float4){acc[0],acc[1],acc[2],acc[3]};
    *(float4*)&aggF[i][q*8+4] = (float4){acc[4],acc[5],acc[6],acc[7]};
    *(uint4*)&Ag[i][q*8] = (uint4){pk2(acc[0],acc[1]),pk2(acc[2],acc[3]),
                                   pk2(acc[4],acc[5]),pk2(acc[6],acc[7])};
    *(uint4*)&Ax[i][q*8] = *(const uint4*)(xb + (size_t)node*128 + q*8);
  }
  __syncthreads();
  const int w = tid>>6, l = tid&63, lr = l&15, lg = l>>4;
  // A fragments: row = lr (16 rows), k = ks*32 + lg*8
  s16x8 ax[4], ag[4];
  #pragma unroll
  for (int ks=0;ks<4;++ks){
    ax[ks] = *(const s16x8*)&Ax[lr][ks*32+lg*8];
    ag[ks] = *(const s16x8*)&Ag[lr][ks*32+lg*8];
  }
  float rr[2][4], zz[2][4];
  #pragma unroll
  for (int c=0;c<3;++c){
    f32x4 aI[2], aH[2];
    #pragma unroll
    for (int i=0;i<2;++i){ aI[i]=(f32x4){0.f,0.f,0.f,0.f}; aH[i]=(f32x4){0.f,0.f,0.f,0.f}; }
    #pragma unroll
    for (int ks=0;ks<4;++ks){
      #pragma unroll
      for (int n2=0;n2<2;++n2){
        int col = w*32 + n2*16 + lr;
        s16x8 bI = *(const s16x8*)(WiB + ((c*128 + col)*128 + ks*32 + lg*8));
        s16x8 bH = *(const s16x8*)(WhB + ((c*128 + col)*128 + ks*32 + lg*8));
        aI[n2] = __builtin_amdgcn_mfma_f32_16x16x32_bf16(ax[ks], bI, aI[n2], 0,0,0);
        aH[n2] = __builtin_amdgcn_mfma_f32_16x16x32_bf16(ag[ks], bH, aH[n2], 0,0,0);
      }
    }
    #pragma unroll
    for (int n2=0;n2<2;++n2){
      int d = w*32 + n2*16 + lr;
      float bI = bih[c*128 + d];
      float bH = bhh[c*128 + d];
      #pragma unroll
      for (int j=0;j<4;++j){
        float gi = aI[n2][j] + bI;
        float gh = aH[n2][j] + bH;
        if (c==0){
          rr[n2][j] = sigm(gi + gh);
        } else if (c==1){
          zz[n2][j] = sigm(gi + gh);
        } else {
          float nn = tanhfast(gi + rr[n2][j]*gh);
          int irow = lg*4 + j;
          int node = base + irow;
          float a = aggF[irow][d];
          float z = zz[n2][j];
          emb[(size_t)node*128 + d] = (1.0f - z)*nn + z*a;
        }
      }
    }
  }
}

extern "C" void kernel_launch(void* const* d_in, const int* in_sizes, int n_in,
                              void* d_out, int out_size, void* d_ws, size_t ws_size,
                              hipStream_t stream){
  (void)in_sizes; (void)n_in; (void)out_size;
  const float* x    = (const float*)d_in[0];
  const int*   ei   = (const int*)d_in[1];
  const float* ea   = (const float*)d_in[2];
  const float* We   = (const float*)d_in[4];
  const float* Whu  = (const float*)d_in[5];
  const float* Whw  = (const float*)d_in[6];
  const float* Wa   = (const float*)d_in[7];
  const float* Wi   = (const float*)d_in[8];
  const float* Wh   = (const float*)d_in[9];
  const float* bih  = (const float*)d_in[10];
  const float* bhh  = (const float*)d_in[11];
  float* out = (float*)d_out;
  float* emb = out;
  float* msg = out + (size_t)N_NODES*128;

  if (ws_size < 90600000) return;
  char* ws = (char*)d_ws;
  unsigned short* phi     = (unsigned short*)(ws);                 // 81,920,000
  unsigned short* xb      = (unsigned short*)(ws + 81920000);      //  5,120,000
  unsigned short* WcatB   = (unsigned short*)(ws + 87040000);      //     98,304
  unsigned short* WaB     = (unsigned short*)(ws + 87138304);      //    131,072
  unsigned short* WiB     = (unsigned short*)(ws + 87269376);      //     98,304
  unsigned short* WhB     = (unsigned short*)(ws + 87367680);      //     98,304
  int*            cnt     = (int*)(ws + 87465984);                 //     80,000
  int*            cnt2    = (int*)(ws + 87545984);                 //     80,000 (adjacent to cnt)
  int*            off     = (int*)(ws + 87625984);                 //     80,016
  int*            off2    = (int*)(ws + 87706000);                 //     80,016
  int*            cursor  = (int*)(ws + 87786016);                 //     80,000
  int*            cursor2 = (int*)(ws + 87866016);                 //     80,000
  int*            sorted  = (int*)(ws + 87946016);                 //  1,280,000
  int*            sortedT = (int*)(ws + 89226016);                 //  1,280,000
  int*            nfA     = (int*)(ws + 90506016);                 //     26,672

  hipMemsetAsync(cnt, 0, 160000, stream);   // covers cnt + cnt2
  k_init<<<4582,256,0,stream>>>(We,Whu,Whw,Wa,Wi,Wh,WcatB,WaB,WiB,WhB, ei, cnt, cnt2, x, xb);
  k_scan<<<2,1024,0,stream>>>(cnt, cnt2, off, off2, cursor, cursor2);
  k_mid<<<1277,256,0,stream>>>(off, nfA, ei, cursor, cursor2, sorted, sortedT);
  k_messages<<<5000,256,0,stream>>>(ea, ei, xb, WcatB, msg);
  k_attn<<<NB2,256,0,stream>>>(msg, phi, WaB, off, sorted, nfA);
  k_gg<<<1250,256,0,stream>>>(x, xb, phi, off2, sortedT, WiB, WhB, bih, bhh, emb);
}